// Round 8
// baseline (854.383 us; speedup 1.0000x reference)
//
#include <hip/hip_runtime.h>
#include <hip/hip_bf16.h>
#include <stdint.h>

// FusedLinearCrossEntropyLoss on MI355X (gfx950)
// loss = mean_i( logsumexp_j(x_i . w_j + b_j) - (x_i . w_t(i) + b_t(i)) )
//
// R8: R6's no-LDS fragment-direct GEMM (256x128 block, 4x2 wave tile,
//     2 blocks/CU) + explicit 2-deep register double-buffered K-loop:
//     next k-group's 12 fragment loads are issued BEFORE current group's
//     MFMAs consume their buffer, so the wave waits on vmcnt(12) (older
//     group only) and load latency overlaps MFMA issue. R7's 4x4/1-wave
//     variant regressed (in-order issue + no co-resident wave) — reverted.
//
// Fragment chunk layout (from cast_swz_k): chunk c = R*16 + g covers rows
// R*32..+31, k g*64..+63. data[c*2048 + h*1024 + lane*16 + j] =
//   M[R*32 + (lane&31)][g*64 + (lane>>5)*32 + h*16 + j]

typedef float f16v __attribute__((ext_vector_type(16)));
typedef int v8i __attribute__((ext_vector_type(8)));

__device__ __forceinline__ unsigned pk_fp8(float4 v) {
  int w = 0;
  w = __builtin_amdgcn_cvt_pk_fp8_f32(v.x, v.y, w, false);  // bytes 0,1
  w = __builtin_amdgcn_cvt_pk_fp8_f32(v.z, v.w, w, true);   // bytes 2,3
  return (unsigned)w;
}

// fp32 [N x 1024] -> fp8 fragment-swizzled chunks. One thread = 16 out bytes.
__global__ __launch_bounds__(256) void cast_swz_k(const float* __restrict__ in,
                                                  uint4* __restrict__ out,
                                                  long n16) {
  long t = (long)blockIdx.x * blockDim.x + threadIdx.x;
  long stride = (long)gridDim.x * blockDim.x;
  for (; t < n16; t += stride) {
    long o = t * 16;
    int c = (int)(o >> 11);
    int rem = (int)(o & 2047);
    int h = rem >> 10;
    int lam = (rem >> 4) & 63;
    int row = (c >> 4) * 32 + (lam & 31);
    int k = (c & 15) * 64 + (lam >> 5) * 32 + h * 16;
    const float4* src = (const float4*)(in + (long)row * 1024 + k);
    uint4 oo;
    oo.x = pk_fp8(src[0]); oo.y = pk_fp8(src[1]);
    oo.z = pk_fp8(src[2]); oo.w = pk_fp8(src[3]);
    out[t] = oo;
  }
}

// One block per row: x_y[row] = x[row] . W[safe_t] + bias[safe_t]  (fp32, exact)
__global__ __launch_bounds__(256) void xy_k(const float* __restrict__ x,
                                            const float* __restrict__ w,
                                            const float* __restrict__ bias,
                                            const int* __restrict__ tgt,
                                            float* __restrict__ xy, int H, int V) {
  int row = blockIdx.x;
  int t = tgt[row];
  int st = min(max(t, 0), V - 1);
  const float4* xr = (const float4*)(x + (long)row * H);
  const float4* wr = (const float4*)(w + (long)st * H);
  float s = 0.f;
  int n4 = H >> 2;
  for (int i = threadIdx.x; i < n4; i += 256) {
    float4 a = xr[i], b = wr[i];
    s += a.x * b.x + a.y * b.y + a.z * b.z + a.w * b.w;
  }
  for (int off = 32; off; off >>= 1) s += __shfl_down(s, off, 64);
  __shared__ float sm[4];
  if ((threadIdx.x & 63) == 0) sm[threadIdx.x >> 6] = s;
  __syncthreads();
  if (threadIdx.x == 0) xy[row] = sm[0] + sm[1] + sm[2] + sm[3] + bias[st];
}

__device__ __forceinline__ v8i ld_frag(const char* p) {
  int4 lo = *(const int4*)(p);
  int4 hi = *(const int4*)(p + 1024);
  v8i t;
  t[0] = lo.x; t[1] = lo.y; t[2] = lo.z; t[3] = lo.w;
  t[4] = hi.x; t[5] = hi.y; t[6] = hi.z; t[7] = hi.w;
  return t;
}

// 256x128 block tile, 4 waves in 2x2; each wave 128x64 via 4x2 of 32x32x64.
// No LDS staging; 2-deep register double-buffered K-loop.
// Epilogue: partials[bn][row] = sum_cols exp(logit + bias).
__global__ __launch_bounds__(256, 2)
void gemm_sumexp(const char* __restrict__ Xf, const char* __restrict__ Wf,
                 const float* __restrict__ bias, float* __restrict__ partials,
                 int H, int BT) {
  __shared__ float rowsum[2][256];

  const int tid = threadIdx.x;
  const int w = tid >> 6, lane = tid & 63;
  const int wr = w >> 1, wc = w & 1;
  const int l32 = lane & 31, kh = lane >> 5;
  const int m0 = blockIdx.x * 256, n0 = blockIdx.y * 128;

  f16v acc[4][2];
#pragma unroll
  for (int mi = 0; mi < 4; mi++)
#pragma unroll
    for (int ni = 0; ni < 2; ni++)
#pragma unroll
      for (int r = 0; r < 16; r++) acc[mi][ni][r] = 0.f;

  const int Rb = blockIdx.x * 8 + wr * 4;   // A 32-row chunk-row base
  const int Nb = blockIdx.y * 4 + wc * 2;   // B 32-row chunk-row base

  const char* pa[4];
  const char* pb[2];
#pragma unroll
  for (int mi = 0; mi < 4; mi++)
    pa[mi] = Xf + ((long)(Rb + mi) * 16) * 2048 + lane * 16;
#pragma unroll
  for (int ni = 0; ni < 2; ni++)
    pb[ni] = Wf + ((long)(Nb + ni) * 16) * 2048 + lane * 16;

  const int nG = H >> 6;  // 16 k-groups of 64

  v8i abuf[2][4], bbuf[2][2];
  // prologue: fill buffer 0 with g=0
#pragma unroll
  for (int mi = 0; mi < 4; mi++) { abuf[0][mi] = ld_frag(pa[mi]); pa[mi] += 2048; }
#pragma unroll
  for (int ni = 0; ni < 2; ni++) { bbuf[0][ni] = ld_frag(pb[ni]); pb[ni] += 2048; }

#pragma unroll 2
  for (int g = 0; g < nG - 1; g++) {
    const int cur = g & 1, nxt = cur ^ 1;
    // issue next group's loads FIRST (into the other buffer) — no dependency
    // on current MFMAs, so the wave only waits vmcnt for the older group.
#pragma unroll
    for (int mi = 0; mi < 4; mi++) { abuf[nxt][mi] = ld_frag(pa[mi]); pa[mi] += 2048; }
#pragma unroll
    for (int ni = 0; ni < 2; ni++) { bbuf[nxt][ni] = ld_frag(pb[ni]); pb[ni] += 2048; }
#pragma unroll
    for (int mi = 0; mi < 4; mi++)
#pragma unroll
      for (int ni = 0; ni < 2; ni++)
        acc[mi][ni] = __builtin_amdgcn_mfma_scale_f32_32x32x64_f8f6f4(
            abuf[cur][mi], bbuf[cur][ni], acc[mi][ni], 0, 0,
            0, 127, 0, 127);
  }
  {
    const int cur = (nG - 1) & 1;
#pragma unroll
    for (int mi = 0; mi < 4; mi++)
#pragma unroll
      for (int ni = 0; ni < 2; ni++)
        acc[mi][ni] = __builtin_amdgcn_mfma_scale_f32_32x32x64_f8f6f4(
            abuf[cur][mi], bbuf[cur][ni], acc[mi][ni], 0, 0,
            0, 127, 0, 127);
  }

  // ---- epilogue: per-row sum of exp(logit + bias) ----
  // C/D 32x32 layout: col = lane&31, row = (reg&3) + 8*(reg>>2) + 4*(lane>>5)
  float bv[2];
  bv[0] = bias[n0 + wc * 64 + l32];
  bv[1] = bias[n0 + wc * 64 + 32 + l32];

#pragma unroll
  for (int mi = 0; mi < 4; mi++) {
    float p[16];
#pragma unroll
    for (int r = 0; r < 16; r++) p[r] = 0.f;
#pragma unroll
    for (int ni = 0; ni < 2; ni++)
#pragma unroll
      for (int r = 0; r < 16; r++) p[r] += __expf(acc[mi][ni][r] + bv[ni]);
    // reduce across the 32 columns (lanes within each 32-group)
#pragma unroll
    for (int off = 1; off < 32; off <<= 1)
#pragma unroll
      for (int r = 0; r < 16; r++) p[r] += __shfl_xor(p[r], off, 32);
    if (l32 == 0) {
#pragma unroll
      for (int r = 0; r < 16; r++)
        rowsum[wc][wr * 128 + mi * 32 + (r & 3) + 8 * (r >> 2) + 4 * kh] = p[r];
    }
  }
  __syncthreads();
  partials[(long)blockIdx.y * BT + m0 + tid] = rowsum[0][tid] + rowsum[1][tid];
}

// per-row: lse - x_y ; block partial sums
__global__ __launch_bounds__(256)
void row_reduce(const float* __restrict__ partials, const float* __restrict__ xy,
                const int* __restrict__ tgt, float* __restrict__ bsum,
                float* __restrict__ bcnt, int BT, int nCB) {
  int row = blockIdx.x * 256 + threadIdx.x;
  float S = 0.f;
  for (int b = 0; b < nCB; b++) S += partials[(long)b * BT + row];
  int t = tgt[row];
  bool valid = (t != -100);
  float pr = valid ? (logf(S) - xy[row]) : 0.f;
  float c = valid ? 1.f : 0.f;
  for (int off = 32; off; off >>= 1) {
    pr += __shfl_down(pr, off, 64);
    c += __shfl_down(c, off, 64);
  }
  __shared__ float sp[4], sc[4];
  if ((threadIdx.x & 63) == 0) {
    sp[threadIdx.x >> 6] = pr;
    sc[threadIdx.x >> 6] = c;
  }
  __syncthreads();
  if (threadIdx.x == 0) {
    bsum[blockIdx.x] = sp[0] + sp[1] + sp[2] + sp[3];
    bcnt[blockIdx.x] = sc[0] + sc[1] + sc[2] + sc[3];
  }
}

__global__ void finalize(const float* __restrict__ bsum, const float* __restrict__ bcnt,
                         float* __restrict__ out, int nb) {
  float s = 0.f, c = 0.f;
  for (int i = threadIdx.x; i < nb; i += 64) { s += bsum[i]; c += bcnt[i]; }
  for (int off = 32; off; off >>= 1) {
    s += __shfl_down(s, off, 64);
    c += __shfl_down(c, off, 64);
  }
  if (threadIdx.x == 0) out[0] = s / c;
}

extern "C" void kernel_launch(void* const* d_in, const int* in_sizes, int n_in,
                              void* d_out, int out_size, void* d_ws, size_t ws_size,
                              hipStream_t stream) {
  const float* x = (const float*)d_in[0];
  const int* tgt = (const int*)d_in[1];
  const float* w = (const float*)d_in[2];
  const float* bias = (const float*)d_in[3];
  float* out = (float*)d_out;

  const int BT = in_sizes[1];            // 4096
  const int V = in_sizes[3];             // 32000
  const int H = in_sizes[0] / BT;        // 1024
  const int nCB = V / 128;               // 250 column blocks

  char* ws = (char*)d_ws;
  const long wb_bytes = (long)V * H;     // fp8: 1 B/elem
  const long xb_bytes = (long)BT * H;
  char* Wf = ws;
  char* Xf = ws + wb_bytes;
  float* partials = (float*)(ws + wb_bytes + xb_bytes);
  float* xy = partials + (long)nCB * BT;
  float* bsum = xy + BT;
  float* bcnt = bsum + (BT / 256);

  cast_swz_k<<<8192, 256, 0, stream>>>(w, (uint4*)Wf, (long)V * H / 16);
  cast_swz_k<<<1024, 256, 0, stream>>>(x, (uint4*)Xf, (long)BT * H / 16);
  xy_k<<<BT, 256, 0, stream>>>(x, w, bias, tgt, xy, H, V);
  // grid.x = row-blocks (fast-varying) so consecutive blocks share the W tile in L2
  dim3 grid(BT / 256, nCB);
  gemm_sumexp<<<grid, 256, 0, stream>>>(Xf, Wf, bias, partials, H, BT);
  row_reduce<<<BT / 256, 256, 0, stream>>>(partials, xy, tgt, bsum, bcnt, BT, nCB);
  finalize<<<1, 64, 0, stream>>>(bsum, bcnt, out, BT / 256);
}

// Round 9
// 426.231 us; speedup vs baseline: 2.0045x; 2.0045x over previous
//
#include <hip/hip_runtime.h>
#include <hip/hip_bf16.h>
#include <stdint.h>

// FusedLinearCrossEntropyLoss on MI355X (gfx950)
// loss = mean_i( logsumexp_j(x_i . w_j + b_j) - (x_i . w_t(i) + b_t(i)) )
//
// R9: R6 no-LDS fragment GEMM (R8's 2-deep reg dbuf spilled acc to scratch ->
//     2 GB WRITE_SIZE, reverted). New: A-operand (X) in MX-fp4 (e2m1) with
//     real per-32-element e8m0 scales fed to mfma_scale's per-lane scale_a;
//     B (W) stays fp8 identity-scaled. A-fragment traffic halves (16 B/lane)
//     with NO extra registers -- attacks the measured VMEM-delivery bound.
//
// W fp8 chunk layout (cast_swz_k): chunk c = R*16+g, 2048 B:
//   data[c*2048 + h*1024 + lane*16 + j] = W[R*32+(lane&31)][g*64+(lane>>5)*32+h*16+j]
// X fp4 chunk layout (cast_x_fp4): chunk c = R*16+g, 1024 B (nibbles, k-ascending,
//   low nibble = even element):
//   data[c*1024 + lane*16 + j] holds X[R*32+(lane&31)][g*64+(lane>>5)*32 + 2j, 2j+1]
//   scale Sa[c*64 + lane] = e8m0 for that lane's 32-elem k-block.

typedef float f16v __attribute__((ext_vector_type(16)));
typedef int v8i __attribute__((ext_vector_type(8)));

__device__ __forceinline__ unsigned pk_fp8(float4 v) {
  int w = 0;
  w = __builtin_amdgcn_cvt_pk_fp8_f32(v.x, v.y, w, false);  // bytes 0,1
  w = __builtin_amdgcn_cvt_pk_fp8_f32(v.z, v.w, w, true);   // bytes 2,3
  return (unsigned)w;
}

// fp32 [N x 1024] -> fp8 fragment-swizzled chunks. One thread = 16 out bytes.
__global__ __launch_bounds__(256) void cast_swz_k(const float* __restrict__ in,
                                                  uint4* __restrict__ out,
                                                  long n16) {
  long t = (long)blockIdx.x * blockDim.x + threadIdx.x;
  long stride = (long)gridDim.x * blockDim.x;
  for (; t < n16; t += stride) {
    long o = t * 16;
    int c = (int)(o >> 11);
    int rem = (int)(o & 2047);
    int h = rem >> 10;
    int lam = (rem >> 4) & 63;
    int row = (c >> 4) * 32 + (lam & 31);
    int k = (c & 15) * 64 + (lam >> 5) * 32 + h * 16;
    const float4* src = (const float4*)(in + (long)row * 1024 + k);
    uint4 oo;
    oo.x = pk_fp8(src[0]); oo.y = pk_fp8(src[1]);
    oo.z = pk_fp8(src[2]); oo.w = pk_fp8(src[3]);
    out[t] = oo;
  }
}

// nearest e2m1 code for |y| <= 6 (y pre-scaled)
__device__ __forceinline__ unsigned q_e2m1(float y) {
  unsigned s = (y < 0.f) ? 8u : 0u;
  float a = fabsf(y);
  unsigned m;
  if (a < 2.f)       m = (unsigned)__float2uint_rn(a * 2.f);  // {0,.5,1,1.5,2}
  else if (a < 2.5f) m = 4;   // 2
  else if (a < 3.5f) m = 5;   // 3
  else if (a < 5.f)  m = 6;   // 4
  else               m = 7;   // 6
  return s | m;
}

// X fp32 [BT x H] -> fp4 fragment chunks + per-32-block e8m0 scales.
// One thread = one (chunk, lane): 32 k-elements of one row.
__global__ __launch_bounds__(256)
void cast_x_fp4(const float* __restrict__ in, unsigned char* __restrict__ outf,
                unsigned char* __restrict__ outs, int H, long nT) {
  long t = (long)blockIdx.x * blockDim.x + threadIdx.x;
  if (t >= nT) return;
  int c = (int)(t >> 6), lane = (int)(t & 63);
  int row = (c >> 4) * 32 + (lane & 31);
  int k0 = (c & 15) * 64 + (lane >> 5) * 32;
  const float* src = in + (long)row * H + k0;
  float v[32];
  float amax = 0.f;
#pragma unroll
  for (int j = 0; j < 8; j++) {
    float4 q = *(const float4*)(src + j * 4);
    v[j * 4 + 0] = q.x; v[j * 4 + 1] = q.y; v[j * 4 + 2] = q.z; v[j * 4 + 3] = q.w;
    amax = fmaxf(amax, fmaxf(fmaxf(fabsf(q.x), fabsf(q.y)),
                             fmaxf(fabsf(q.z), fabsf(q.w))));
  }
  int e = 0;
  if (amax > 0.f) {
    e = ilogbf(amax) - 2;
    if (amax > ldexpf(6.f, e)) e++;  // guarantee amax/2^e <= 6 (no clipping)
  }
  float inv = ldexpf(1.f, -e);
  unsigned bytes[16];
#pragma unroll
  for (int j = 0; j < 16; j++) {
    unsigned lo = q_e2m1(v[2 * j] * inv);
    unsigned hi = q_e2m1(v[2 * j + 1] * inv);
    bytes[j] = lo | (hi << 4);
  }
  uint4 oo;
  oo.x = bytes[0] | (bytes[1] << 8) | (bytes[2] << 16) | (bytes[3] << 24);
  oo.y = bytes[4] | (bytes[5] << 8) | (bytes[6] << 16) | (bytes[7] << 24);
  oo.z = bytes[8] | (bytes[9] << 8) | (bytes[10] << 16) | (bytes[11] << 24);
  oo.w = bytes[12] | (bytes[13] << 8) | (bytes[14] << 16) | (bytes[15] << 24);
  *(uint4*)(outf + (long)c * 1024 + lane * 16) = oo;
  outs[(long)c * 64 + lane] = (unsigned char)(e + 127);
}

// One block per row: x_y[row] = x[row] . W[safe_t] + bias[safe_t]  (fp32, exact)
__global__ __launch_bounds__(256) void xy_k(const float* __restrict__ x,
                                            const float* __restrict__ w,
                                            const float* __restrict__ bias,
                                            const int* __restrict__ tgt,
                                            float* __restrict__ xy, int H, int V) {
  int row = blockIdx.x;
  int t = tgt[row];
  int st = min(max(t, 0), V - 1);
  const float4* xr = (const float4*)(x + (long)row * H);
  const float4* wr = (const float4*)(w + (long)st * H);
  float s = 0.f;
  int n4 = H >> 2;
  for (int i = threadIdx.x; i < n4; i += 256) {
    float4 a = xr[i], b = wr[i];
    s += a.x * b.x + a.y * b.y + a.z * b.z + a.w * b.w;
  }
  for (int off = 32; off; off >>= 1) s += __shfl_down(s, off, 64);
  __shared__ float sm[4];
  if ((threadIdx.x & 63) == 0) sm[threadIdx.x >> 6] = s;
  __syncthreads();
  if (threadIdx.x == 0) xy[row] = sm[0] + sm[1] + sm[2] + sm[3] + bias[st];
}

// 256x128 block tile, 4 waves in 2x2; each wave 128x64 via 4x2 of 32x32x64.
// A = MX-fp4 (per-lane e8m0 scale), B = fp8 identity. No LDS staging.
// Epilogue: partials[bn][row] = sum_cols exp(logit + bias).
__global__ __launch_bounds__(256, 2)
void gemm_sumexp(const unsigned char* __restrict__ Xf,
                 const unsigned char* __restrict__ Sa,
                 const char* __restrict__ Wf,
                 const float* __restrict__ bias, float* __restrict__ partials,
                 int H, int BT) {
  __shared__ float rowsum[2][256];

  const int tid = threadIdx.x;
  const int w = tid >> 6, lane = tid & 63;
  const int wr = w >> 1, wc = w & 1;
  const int l32 = lane & 31, kh = lane >> 5;
  const int m0 = blockIdx.x * 256, n0 = blockIdx.y * 128;

  f16v acc[4][2];
#pragma unroll
  for (int mi = 0; mi < 4; mi++)
#pragma unroll
    for (int ni = 0; ni < 2; ni++)
#pragma unroll
      for (int r = 0; r < 16; r++) acc[mi][ni][r] = 0.f;

  const int Rb = blockIdx.x * 8 + wr * 4;   // A 32-row chunk-row base
  const int Nb = blockIdx.y * 4 + wc * 2;   // B 32-row chunk-row base

  const unsigned char* pa[4];
  const unsigned char* ps[4];
  const char* pb[2];
#pragma unroll
  for (int mi = 0; mi < 4; mi++) {
    pa[mi] = Xf + ((long)(Rb + mi) * 16) * 1024 + lane * 16;
    ps[mi] = Sa + ((long)(Rb + mi) * 16) * 64 + lane;
  }
#pragma unroll
  for (int ni = 0; ni < 2; ni++)
    pb[ni] = Wf + ((long)(Nb + ni) * 16) * 2048 + lane * 16;

  const int nG = H >> 6;  // 16 k-groups of 64
#pragma unroll 4
  for (int g = 0; g < nG; g++) {
    // B first (oldest in flight -> needed by first MFMA), then scales, then A
    v8i b[2];
#pragma unroll
    for (int ni = 0; ni < 2; ni++) {
      int4 lo = *(const int4*)(pb[ni]);
      int4 hi = *(const int4*)(pb[ni] + 1024);
      v8i t;
      t[0] = lo.x; t[1] = lo.y; t[2] = lo.z; t[3] = lo.w;
      t[4] = hi.x; t[5] = hi.y; t[6] = hi.z; t[7] = hi.w;
      b[ni] = t;
      pb[ni] += 2048;
    }
    int sca[4];
    v8i a[4];
#pragma unroll
    for (int mi = 0; mi < 4; mi++) {
      sca[mi] = (int)(*ps[mi]);
      ps[mi] += 64;
      int4 lo = *(const int4*)(pa[mi]);
      v8i t;
      t[0] = lo.x; t[1] = lo.y; t[2] = lo.z; t[3] = lo.w;
      t[4] = 0; t[5] = 0; t[6] = 0; t[7] = 0;
      a[mi] = t;
      pa[mi] += 1024;
    }
#pragma unroll
    for (int mi = 0; mi < 4; mi++)
#pragma unroll
      for (int ni = 0; ni < 2; ni++)
        acc[mi][ni] = __builtin_amdgcn_mfma_scale_f32_32x32x64_f8f6f4(
            a[mi], b[ni], acc[mi][ni], 4 /*A=fp4 e2m1*/, 0 /*B=fp8 e4m3*/,
            0, sca[mi] /*per-lane e8m0*/, 0, 127 /*scale_b = 1.0*/);
  }

  // ---- epilogue: per-row sum of exp(logit + bias) ----
  // C/D 32x32 layout: col = lane&31, row = (reg&3) + 8*(reg>>2) + 4*(lane>>5)
  float bv[2];
  bv[0] = bias[n0 + wc * 64 + l32];
  bv[1] = bias[n0 + wc * 64 + 32 + l32];

#pragma unroll
  for (int mi = 0; mi < 4; mi++) {
    float p[16];
#pragma unroll
    for (int r = 0; r < 16; r++) p[r] = 0.f;
#pragma unroll
    for (int ni = 0; ni < 2; ni++)
#pragma unroll
      for (int r = 0; r < 16; r++) p[r] += __expf(acc[mi][ni][r] + bv[ni]);
    // reduce across the 32 columns (lanes within each 32-group)
#pragma unroll
    for (int off = 1; off < 32; off <<= 1)
#pragma unroll
      for (int r = 0; r < 16; r++) p[r] += __shfl_xor(p[r], off, 32);
    if (l32 == 0) {
#pragma unroll
      for (int r = 0; r < 16; r++)
        rowsum[wc][wr * 128 + mi * 32 + (r & 3) + 8 * (r >> 2) + 4 * kh] = p[r];
    }
  }
  __syncthreads();
  partials[(long)blockIdx.y * BT + m0 + tid] = rowsum[0][tid] + rowsum[1][tid];
}

// per-row: lse - x_y ; block partial sums
__global__ __launch_bounds__(256)
void row_reduce(const float* __restrict__ partials, const float* __restrict__ xy,
                const int* __restrict__ tgt, float* __restrict__ bsum,
                float* __restrict__ bcnt, int BT, int nCB) {
  int row = blockIdx.x * 256 + threadIdx.x;
  float S = 0.f;
  for (int b = 0; b < nCB; b++) S += partials[(long)b * BT + row];
  int t = tgt[row];
  bool valid = (t != -100);
  float pr = valid ? (logf(S) - xy[row]) : 0.f;
  float c = valid ? 1.f : 0.f;
  for (int off = 32; off; off >>= 1) {
    pr += __shfl_down(pr, off, 64);
    c += __shfl_down(c, off, 64);
  }
  __shared__ float sp[4], sc[4];
  if ((threadIdx.x & 63) == 0) {
    sp[threadIdx.x >> 6] = pr;
    sc[threadIdx.x >> 6] = c;
  }
  __syncthreads();
  if (threadIdx.x == 0) {
    bsum[blockIdx.x] = sp[0] + sp[1] + sp[2] + sp[3];
    bcnt[blockIdx.x] = sc[0] + sc[1] + sc[2] + sc[3];
  }
}

__global__ void finalize(const float* __restrict__ bsum, const float* __restrict__ bcnt,
                         float* __restrict__ out, int nb) {
  float s = 0.f, c = 0.f;
  for (int i = threadIdx.x; i < nb; i += 64) { s += bsum[i]; c += bcnt[i]; }
  for (int off = 32; off; off >>= 1) {
    s += __shfl_down(s, off, 64);
    c += __shfl_down(c, off, 64);
  }
  if (threadIdx.x == 0) out[0] = s / c;
}

extern "C" void kernel_launch(void* const* d_in, const int* in_sizes, int n_in,
                              void* d_out, int out_size, void* d_ws, size_t ws_size,
                              hipStream_t stream) {
  const float* x = (const float*)d_in[0];
  const int* tgt = (const int*)d_in[1];
  const float* w = (const float*)d_in[2];
  const float* bias = (const float*)d_in[3];
  float* out = (float*)d_out;

  const int BT = in_sizes[1];            // 4096
  const int V = in_sizes[3];             // 32000
  const int H = in_sizes[0] / BT;        // 1024
  const int nCB = V / 128;               // 250 column blocks

  char* ws = (char*)d_ws;
  const long wb_bytes = (long)V * H;         // W fp8: 32 MB
  const long xf_bytes = (long)BT * H / 2;    // X fp4: 2 MB
  const long sa_bytes = (long)BT * H / 32;   // X scales: 128 KB
  char* Wf = ws;
  unsigned char* Xf = (unsigned char*)(ws + wb_bytes);
  unsigned char* Sa = (unsigned char*)(ws + wb_bytes + xf_bytes);
  float* partials = (float*)(ws + wb_bytes + xf_bytes + sa_bytes);
  float* xy = partials + (long)nCB * BT;
  float* bsum = xy + BT;
  float* bcnt = bsum + (BT / 256);

  cast_swz_k<<<8192, 256, 0, stream>>>(w, (uint4*)Wf, (long)V * H / 16);
  long nT = (long)BT * H / 32;               // one thread per 32-elem block
  cast_x_fp4<<<(int)((nT + 255) / 256), 256, 0, stream>>>(x, Xf, Sa, H, nT);
  xy_k<<<BT, 256, 0, stream>>>(x, w, bias, tgt, xy, H, V);
  // grid.x = row-blocks (fast-varying) so consecutive blocks share the W tile in L2
  dim3 grid(BT / 256, nCB);
  gemm_sumexp<<<grid, 256, 0, stream>>>(Xf, Sa, Wf, bias, partials, H, BT);
  row_reduce<<<BT / 256, 256, 0, stream>>>(partials, xy, tgt, bsum, bcnt, BT, nCB);
  finalize<<<1, 64, 0, stream>>>(bsum, bcnt, out, BT / 256);
}

// Round 10
// 425.243 us; speedup vs baseline: 2.0092x; 1.0023x over previous
//
#include <hip/hip_runtime.h>
#include <hip/hip_bf16.h>
#include <stdint.h>

// FusedLinearCrossEntropyLoss on MI355X (gfx950)
// loss = mean_i( logsumexp_j(x_i . w_j + b_j) - (x_i . w_t(i) + b_t(i)) )
//
// R10: occupancy model (512 unified regs / (VGPR+AGPR)) says acc=128 caps us
//      at 2 waves/SIMD and the loop is latency-bound. Wave tile shrunk to
//      128x32 (acc 64), block 128x128 with 4 waves -> target 4 waves/SIMD.
//      BOTH operands now MX-fp4 (e2m1 + per-32-elem e8m0 scales): fragment
//      regs halve AND fp4xfp4 runs the 32x32x64 f8f6f4 MFMA at 2x fp8 rate
//      (m59: 9099 vs 4686 TF) -> MFMA floor 57 -> ~29 us.
//
// fp4 chunk layout (cast_mx4, H=1024 -> 16 k-groups): chunk c = rb*16 + g
// covers rows rb*32..+31, k g*64..+63. 1024 B/chunk:
//   data[c*1024 + lane*16 + j] = nibbles of M[rb*32+(lane&31)]
//        [g*64 + (lane>>5)*32 + 2j, 2j+1]  (low nibble = even elem)
//   scale[c*64 + lane] = e8m0 for that lane's 32-elem k-block.

typedef float f16v __attribute__((ext_vector_type(16)));
typedef int v8i __attribute__((ext_vector_type(8)));

// nearest e2m1 code for |y| <= 6 (y pre-scaled)
__device__ __forceinline__ unsigned q_e2m1(float y) {
  unsigned s = (y < 0.f) ? 8u : 0u;
  float a = fabsf(y);
  unsigned m;
  if (a < 2.f)       m = (unsigned)__float2uint_rn(a * 2.f);  // {0,.5,1,1.5,2}
  else if (a < 2.5f) m = 4;   // 2
  else if (a < 3.5f) m = 5;   // 3
  else if (a < 5.f)  m = 6;   // 4
  else               m = 7;   // 6
  return s | m;
}

// fp32 [rows x 1024] -> MX-fp4 fragment chunks + per-32-block e8m0 scales.
// One thread = one (chunk, lane): 32 k-elements of one row. H must be 1024.
__global__ __launch_bounds__(256)
void cast_mx4(const float* __restrict__ in, unsigned char* __restrict__ outf,
              unsigned char* __restrict__ outs, int H, long nT) {
  long t = (long)blockIdx.x * blockDim.x + threadIdx.x;
  if (t >= nT) return;
  int c = (int)(t >> 6), lane = (int)(t & 63);
  int row = (c >> 4) * 32 + (lane & 31);
  int k0 = (c & 15) * 64 + (lane >> 5) * 32;
  const float* src = in + (long)row * H + k0;
  float v[32];
  float amax = 0.f;
#pragma unroll
  for (int j = 0; j < 8; j++) {
    float4 q = *(const float4*)(src + j * 4);
    v[j * 4 + 0] = q.x; v[j * 4 + 1] = q.y; v[j * 4 + 2] = q.z; v[j * 4 + 3] = q.w;
    amax = fmaxf(amax, fmaxf(fmaxf(fabsf(q.x), fabsf(q.y)),
                             fmaxf(fabsf(q.z), fabsf(q.w))));
  }
  int e = 0;
  if (amax > 0.f) {
    e = ilogbf(amax) - 2;
    if (amax > ldexpf(6.f, e)) e++;  // guarantee amax/2^e <= 6 (no clipping)
  }
  float inv = ldexpf(1.f, -e);
  unsigned bytes[16];
#pragma unroll
  for (int j = 0; j < 16; j++) {
    unsigned lo = q_e2m1(v[2 * j] * inv);
    unsigned hi = q_e2m1(v[2 * j + 1] * inv);
    bytes[j] = lo | (hi << 4);
  }
  uint4 oo;
  oo.x = bytes[0] | (bytes[1] << 8) | (bytes[2] << 16) | (bytes[3] << 24);
  oo.y = bytes[4] | (bytes[5] << 8) | (bytes[6] << 16) | (bytes[7] << 24);
  oo.z = bytes[8] | (bytes[9] << 8) | (bytes[10] << 16) | (bytes[11] << 24);
  oo.w = bytes[12] | (bytes[13] << 8) | (bytes[14] << 16) | (bytes[15] << 24);
  *(uint4*)(outf + (long)c * 1024 + lane * 16) = oo;
  outs[(long)c * 64 + lane] = (unsigned char)(e + 127);
}

// One block per row: x_y[row] = x[row] . W[safe_t] + bias[safe_t]  (fp32, exact)
__global__ __launch_bounds__(256) void xy_k(const float* __restrict__ x,
                                            const float* __restrict__ w,
                                            const float* __restrict__ bias,
                                            const int* __restrict__ tgt,
                                            float* __restrict__ xy, int H, int V) {
  int row = blockIdx.x;
  int t = tgt[row];
  int st = min(max(t, 0), V - 1);
  const float4* xr = (const float4*)(x + (long)row * H);
  const float4* wr = (const float4*)(w + (long)st * H);
  float s = 0.f;
  int n4 = H >> 2;
  for (int i = threadIdx.x; i < n4; i += 256) {
    float4 a = xr[i], b = wr[i];
    s += a.x * b.x + a.y * b.y + a.z * b.z + a.w * b.w;
  }
  for (int off = 32; off; off >>= 1) s += __shfl_down(s, off, 64);
  __shared__ float sm[4];
  if ((threadIdx.x & 63) == 0) sm[threadIdx.x >> 6] = s;
  __syncthreads();
  if (threadIdx.x == 0) xy[row] = sm[0] + sm[1] + sm[2] + sm[3] + bias[st];
}

// 128x128 block tile, 4 waves; wave wc owns col strip wc*32, wave tile 128x32
// via 4x1 of 32x32x64 fp4xfp4 scaled MFMAs (acc 64 regs). No LDS staging.
// Epilogue: partials[bn][row] = sum_cols exp(logit + bias).
__global__ __launch_bounds__(256, 4)
void gemm_sumexp(const unsigned char* __restrict__ Xf,
                 const unsigned char* __restrict__ Sax,
                 const unsigned char* __restrict__ Wf,
                 const unsigned char* __restrict__ Saw,
                 const float* __restrict__ bias, float* __restrict__ partials,
                 int H, int BT) {
  __shared__ float rowsum[4][128];

  const int tid = threadIdx.x;
  const int wc = tid >> 6, lane = tid & 63;
  const int l32 = lane & 31, kh = lane >> 5;
  const int m0 = blockIdx.x * 128, n0 = blockIdx.y * 128;

  f16v acc[4];
#pragma unroll
  for (int mi = 0; mi < 4; mi++)
#pragma unroll
    for (int r = 0; r < 16; r++) acc[mi][r] = 0.f;

  const int Rb = blockIdx.x * 4;            // A 32-row chunk-row base
  const int Nb = blockIdx.y * 4 + wc;       // B chunk-row (this wave's strip)

  const unsigned char* pa[4];
  const unsigned char* psa[4];
#pragma unroll
  for (int mi = 0; mi < 4; mi++) {
    pa[mi] = Xf + ((long)(Rb + mi) * 16) * 1024 + lane * 16;
    psa[mi] = Sax + ((long)(Rb + mi) * 16) * 64 + lane;
  }
  const unsigned char* pb = Wf + ((long)Nb * 16) * 1024 + lane * 16;
  const unsigned char* psb = Saw + ((long)Nb * 16) * 64 + lane;

  const int nG = H >> 6;  // 16 k-groups of 64
#pragma unroll 4
  for (int g = 0; g < nG; g++) {
    int4 b4 = *(const int4*)pb;  pb += 1024;
    int scb = (int)(*psb);       psb += 64;
    v8i b;
    b[0] = b4.x; b[1] = b4.y; b[2] = b4.z; b[3] = b4.w;
    b[4] = 0; b[5] = 0; b[6] = 0; b[7] = 0;
    int4 a4[4];
    int sca[4];
#pragma unroll
    for (int mi = 0; mi < 4; mi++) {
      a4[mi] = *(const int4*)pa[mi]; pa[mi] += 1024;
      sca[mi] = (int)(*psa[mi]);     psa[mi] += 64;
    }
#pragma unroll
    for (int mi = 0; mi < 4; mi++) {
      v8i a;
      a[0] = a4[mi].x; a[1] = a4[mi].y; a[2] = a4[mi].z; a[3] = a4[mi].w;
      a[4] = 0; a[5] = 0; a[6] = 0; a[7] = 0;
      acc[mi] = __builtin_amdgcn_mfma_scale_f32_32x32x64_f8f6f4(
          a, b, acc[mi], 4 /*A=fp4 e2m1*/, 4 /*B=fp4 e2m1*/,
          0, sca[mi], 0, scb);
    }
  }

  // ---- epilogue: per-row sum of exp(logit + bias) ----
  // C/D 32x32 layout: col = lane&31, row = (reg&3) + 8*(reg>>2) + 4*(lane>>5)
  const float bv = bias[n0 + wc * 32 + l32];

#pragma unroll
  for (int mi = 0; mi < 4; mi++) {
    float p[16];
#pragma unroll
    for (int r = 0; r < 16; r++) p[r] = __expf(acc[mi][r] + bv);
    // reduce across the 32 columns (lanes within each 32-group)
#pragma unroll
    for (int off = 1; off < 32; off <<= 1)
#pragma unroll
      for (int r = 0; r < 16; r++) p[r] += __shfl_xor(p[r], off, 32);
    if (l32 == 0) {
#pragma unroll
      for (int r = 0; r < 16; r++)
        rowsum[wc][mi * 32 + (r & 3) + 8 * (r >> 2) + 4 * kh] = p[r];
    }
  }
  __syncthreads();
  if (tid < 128)
    partials[(long)blockIdx.y * BT + m0 + tid] =
        rowsum[0][tid] + rowsum[1][tid] + rowsum[2][tid] + rowsum[3][tid];
}

// per-row: lse - x_y ; block partial sums
__global__ __launch_bounds__(256)
void row_reduce(const float* __restrict__ partials, const float* __restrict__ xy,
                const int* __restrict__ tgt, float* __restrict__ bsum,
                float* __restrict__ bcnt, int BT, int nCB) {
  int row = blockIdx.x * 256 + threadIdx.x;
  float S = 0.f;
  for (int b = 0; b < nCB; b++) S += partials[(long)b * BT + row];
  int t = tgt[row];
  bool valid = (t != -100);
  float pr = valid ? (logf(S) - xy[row]) : 0.f;
  float c = valid ? 1.f : 0.f;
  for (int off = 32; off; off >>= 1) {
    pr += __shfl_down(pr, off, 64);
    c += __shfl_down(c, off, 64);
  }
  __shared__ float sp[4], sc[4];
  if ((threadIdx.x & 63) == 0) {
    sp[threadIdx.x >> 6] = pr;
    sc[threadIdx.x >> 6] = c;
  }
  __syncthreads();
  if (threadIdx.x == 0) {
    bsum[blockIdx.x] = sp[0] + sp[1] + sp[2] + sp[3];
    bcnt[blockIdx.x] = sc[0] + sc[1] + sc[2] + sc[3];
  }
}

__global__ void finalize(const float* __restrict__ bsum, const float* __restrict__ bcnt,
                         float* __restrict__ out, int nb) {
  float s = 0.f, c = 0.f;
  for (int i = threadIdx.x; i < nb; i += 64) { s += bsum[i]; c += bcnt[i]; }
  for (int off = 32; off; off >>= 1) {
    s += __shfl_down(s, off, 64);
    c += __shfl_down(c, off, 64);
  }
  if (threadIdx.x == 0) out[0] = s / c;
}

extern "C" void kernel_launch(void* const* d_in, const int* in_sizes, int n_in,
                              void* d_out, int out_size, void* d_ws, size_t ws_size,
                              hipStream_t stream) {
  const float* x = (const float*)d_in[0];
  const int* tgt = (const int*)d_in[1];
  const float* w = (const float*)d_in[2];
  const float* bias = (const float*)d_in[3];
  float* out = (float*)d_out;

  const int BT = in_sizes[1];            // 4096
  const int V = in_sizes[3];             // 32000
  const int H = in_sizes[0] / BT;        // 1024
  const int nCB = V / 128;               // 250 column blocks

  char* ws = (char*)d_ws;
  const long wf_bytes = (long)V * H / 2;     // W fp4: 16 MB
  const long sw_bytes = (long)V * H / 32;    // W scales: 1 MB
  const long xf_bytes = (long)BT * H / 2;    // X fp4: 2 MB
  const long sx_bytes = (long)BT * H / 32;   // X scales: 128 KB
  unsigned char* Wf = (unsigned char*)ws;
  unsigned char* Saw = (unsigned char*)(ws + wf_bytes);
  unsigned char* Xf = (unsigned char*)(ws + wf_bytes + sw_bytes);
  unsigned char* Sax = (unsigned char*)(ws + wf_bytes + sw_bytes + xf_bytes);
  float* partials = (float*)(ws + wf_bytes + sw_bytes + xf_bytes + sx_bytes);
  float* xy = partials + (long)nCB * BT;
  float* bsum = xy + BT;
  float* bcnt = bsum + (BT / 256);

  long nTw = (long)V * H / 32;               // one thread per 32-elem block
  long nTx = (long)BT * H / 32;
  cast_mx4<<<(int)((nTw + 255) / 256), 256, 0, stream>>>(w, Wf, Saw, H, nTw);
  cast_mx4<<<(int)((nTx + 255) / 256), 256, 0, stream>>>(x, Xf, Sax, H, nTx);
  xy_k<<<BT, 256, 0, stream>>>(x, w, bias, tgt, xy, H, V);
  // grid.x = row-blocks (fast-varying) so consecutive blocks share the W tile in L2
  dim3 grid(BT / 128, nCB);
  gemm_sumexp<<<grid, 256, 0, stream>>>(Xf, Sax, Wf, Saw, bias, partials, H, BT);
  row_reduce<<<BT / 256, 256, 0, stream>>>(partials, xy, tgt, bsum, bcnt, BT, nCB);
  finalize<<<1, 64, 0, stream>>>(bsum, bcnt, out, BT / 256);
}